// Round 17
// baseline (940.026 us; speedup 1.0000x reference)
//
#include <hip/hip_runtime.h>

#define HF 64     // hidden feature width
#define CHUNK 32  // edges staged per wave per round

typedef __attribute__((address_space(1))) const void gvoid;
typedef __attribute__((address_space(3))) void lvoid;

// ---------------- CSR build: histogram ----------------
__global__ void hist_kernel(const int* __restrict__ dst, int* __restrict__ deg, int E) {
    int e = blockIdx.x * blockDim.x + threadIdx.x;
    if (e < E) atomicAdd(&deg[dst[e]], 1);
}

__global__ __launch_bounds__(256) void scan_partial(const int* __restrict__ deg,
                                                    int* __restrict__ blocksum, int N) {
    __shared__ int red[256];
    int base = blockIdx.x * 1024 + threadIdx.x * 4;
    int s = 0;
#pragma unroll
    for (int j = 0; j < 4; ++j) {
        int i = base + j;
        if (i < N) s += deg[i];
    }
    red[threadIdx.x] = s;
    __syncthreads();
    for (int o = 128; o > 0; o >>= 1) {
        if (threadIdx.x < o) red[threadIdx.x] += red[threadIdx.x + o];
        __syncthreads();
    }
    if (threadIdx.x == 0) blocksum[blockIdx.x] = red[0];
}

__global__ __launch_bounds__(256) void scan_blocksums(int* __restrict__ blocksum, int nb) {
    __shared__ int lds[256];
    int t = threadIdx.x;
    int v = (t < nb) ? blocksum[t] : 0;
    lds[t] = v;
    __syncthreads();
    for (int o = 1; o < 256; o <<= 1) {
        int add = (t >= o) ? lds[t - o] : 0;
        __syncthreads();
        lds[t] += add;
        __syncthreads();
    }
    if (t < nb) blocksum[t] = lds[t] - v;  // exclusive
}

__global__ __launch_bounds__(256) void scan_apply(const int* __restrict__ deg,
                                                  const int* __restrict__ blocksum,
                                                  int* __restrict__ cursor,
                                                  float* __restrict__ dinv, int N) {
    __shared__ int lds[256];
    int base = blockIdx.x * 1024 + threadIdx.x * 4;
    int v[4];
    int s = 0;
#pragma unroll
    for (int j = 0; j < 4; ++j) {
        int i = base + j;
        v[j] = (i < N) ? deg[i] : 0;
        s += v[j];
    }
    lds[threadIdx.x] = s;
    __syncthreads();
    for (int o = 1; o < 256; o <<= 1) {
        int add = (threadIdx.x >= o) ? lds[threadIdx.x - o] : 0;
        __syncthreads();
        lds[threadIdx.x] += add;
        __syncthreads();
    }
    int run = blocksum[blockIdx.x] + lds[threadIdx.x] - s;
#pragma unroll
    for (int j = 0; j < 4; ++j) {
        int i = base + j;
        if (i < N) {
            cursor[i] = run;
            dinv[i] = rsqrtf((float)v[j] + 1.0f);
            run += v[j];
        }
    }
}

// XCD-partitioned fill (round-16: removed the 16x write amplification; keep as-is)
__global__ __launch_bounds__(256) void fill_kernel(const int* __restrict__ src,
                                                   const int* __restrict__ dst,
                                                   int* __restrict__ cursor,
                                                   int* __restrict__ csr_src,
                                                   int E, int part, int nblk) {
    int p = blockIdx.x & 7;
    int blk = blockIdx.x >> 3;
    int plo = p * part;
    int phi = plo + part;
    for (int e = blk * 256 + threadIdx.x; e < E; e += nblk * 256) {
        int d = dst[e];
        if (d >= plo && d < phi) {
            int pos = atomicAdd(&cursor[d], 1);
            csr_src[pos] = src[e];
        }
    }
}

// ---------------- node GEMM: Y[n][f] = (sum_k X[n][k] W[k][f]) * scale[n] (fp32) ----------
template <int K>
__global__ __launch_bounds__(256) void gemm_scale_kernel(const float* __restrict__ X,
                                                         const float* __restrict__ W,
                                                         const float* __restrict__ scale,
                                                         float* __restrict__ Y, int N) {
    __shared__ float Wl[K * HF];
    __shared__ float xs[32 * K];
    for (int i = threadIdx.x; i < K * HF; i += 256) Wl[i] = W[i];

    int node0 = blockIdx.x * 32;
    const float4* X4 = (const float4*)(X + (size_t)node0 * K);
    float4* xs4 = (float4*)xs;
    int totalf4 = 32 * K / 4;
    for (int i = threadIdx.x; i < totalf4; i += 256) {
        int n = i / (K / 4);
        if (node0 + n < N) xs4[i] = X4[i];
    }
    __syncthreads();

    int wave = threadIdx.x >> 6, f = threadIdx.x & 63;
    for (int n = wave; n < 32; n += 4) {
        int node = node0 + n;
        if (node >= N) break;
        const float4* xr = (const float4*)&xs[n * K];
        float acc = 0.0f;
#pragma unroll
        for (int k4 = 0; k4 < K / 4; ++k4) {
            float4 xv = xr[k4];
            acc += xv.x * Wl[(k4 * 4 + 0) * HF + f];
            acc += xv.y * Wl[(k4 * 4 + 1) * HF + f];
            acc += xv.z * Wl[(k4 * 4 + 2) * HF + f];
            acc += xv.w * Wl[(k4 * 4 + 3) * HF + f];
        }
        Y[(size_t)node * HF + f] = acc * scale[node];
    }
}

// ---- gather-sum via global_load_lds: fire-and-forget direct-to-LDS row loads ----
// Per chunk: issue up to 32 loads (no dest VGPR -> compiler CANNOT collapse the
// pipeline; vmcnt tracks them), wait once, then conflict-free ds_read + add.
__device__ __forceinline__ float edge_gather_sum(const float* __restrict__ hs,
                                                 const int* __restrict__ csr_src,
                                                 int beg, int end, int lane,
                                                 float* __restrict__ wstage) {
    float acc = 0.0f;
    for (int base = beg; base < end; base += CHUNK) {
        int li = base + (lane & 31);
        int myidx = csr_src[li < end ? li : beg];  // clamped: tail lanes read safe idx
        int rem = end - base;
        if (rem > CHUNK) rem = CHUNK;
        for (int j = 0; j < rem; ++j) {  // wave-uniform trip count
            int s = __builtin_amdgcn_readlane(myidx, j);
            const float* gp = hs + (size_t)s * HF + lane;  // per-lane: 64x4B = full row
            __builtin_amdgcn_global_load_lds((gvoid*)gp, (lvoid*)(wstage + j * HF), 4, 0, 0);
        }
        asm volatile("s_waitcnt vmcnt(0)" ::: "memory");
        for (int j = 0; j < rem; ++j) acc += wstage[j * HF + lane];
        asm volatile("s_waitcnt lgkmcnt(0)" ::: "memory");  // reads done before re-stage
    }
    return acc;
}

// ---------------- conv1 aggregation + epilogue: out = relu(dinv*(agg+self) + b) ----------
__global__ __launch_bounds__(256) void agg_relu_kernel(const float* __restrict__ hs,
                                                       const int* __restrict__ cursor,
                                                       const int* __restrict__ deg,
                                                       const int* __restrict__ csr_src,
                                                       const float* __restrict__ dinv,
                                                       const float* __restrict__ b,
                                                       float* __restrict__ out, int N) {
    __shared__ float stage[4][CHUNK * HF];
    int wave = threadIdx.x >> 6;
    int d = blockIdx.x * 4 + wave;
    if (d >= N) return;
    int f = threadIdx.x & 63;
    int end = cursor[d];
    int beg = end - deg[d];
    float acc = edge_gather_sum(hs, csr_src, beg, end, f, stage[wave]);
    float v = dinv[d] * (acc + hs[(size_t)d * HF + f]) + b[f];
    out[(size_t)d * HF + f] = fmaxf(v, 0.0f);
}

// ---------------- conv2 aggregation + relu + mean-pool accumulation ----------------
__global__ __launch_bounds__(256) void agg_pool_kernel(const float* __restrict__ hs,
                                                       const int* __restrict__ cursor,
                                                       const int* __restrict__ deg,
                                                       const int* __restrict__ csr_src,
                                                       const float* __restrict__ dinv,
                                                       const float* __restrict__ b,
                                                       const int* __restrict__ batch,
                                                       float* __restrict__ pool,
                                                       float* __restrict__ cnt, int N) {
    __shared__ float stage[4][CHUNK * HF];
    int wave = threadIdx.x >> 6;
    int d = blockIdx.x * 4 + wave;
    if (d >= N) return;
    int f = threadIdx.x & 63;
    int end = cursor[d];
    int beg = end - deg[d];
    float acc = edge_gather_sum(hs, csr_src, beg, end, f, stage[wave]);
    float v = fmaxf(dinv[d] * (acc + hs[(size_t)d * HF + f]) + b[f], 0.0f);
    int g = batch[d];
    atomicAdd(&pool[g * HF + f], v);
    if (f == 0) atomicAdd(&cnt[g], 1.0f);
}

// ---------------- final: out[g][c] = (pool[g]/cnt[g]) @ Wlin + blin ---------------------
__global__ void final_kernel(const float* __restrict__ pool, const float* __restrict__ cnt,
                             const float* __restrict__ Wlin, const float* __restrict__ blin,
                             float* __restrict__ out) {
    int g = blockIdx.x;
    int f = threadIdx.x;  // 64
    float v = pool[g * HF + f] / fmaxf(cnt[g], 1.0f);
    float s0 = v * Wlin[f * 2 + 0];
    float s1 = v * Wlin[f * 2 + 1];
#pragma unroll
    for (int off = 32; off > 0; off >>= 1) {
        s0 += __shfl_down(s0, off);
        s1 += __shfl_down(s1, off);
    }
    if (f == 0) {
        out[g * 2 + 0] = s0 + blin[0];
        out[g * 2 + 1] = s1 + blin[1];
    }
}

extern "C" void kernel_launch(void* const* d_in, const int* in_sizes, int n_in,
                              void* d_out, int out_size, void* d_ws, size_t ws_size,
                              hipStream_t stream) {
    const float* x    = (const float*)d_in[0];
    const int*   ei   = (const int*)d_in[1];
    const int*   bat  = (const int*)d_in[2];
    const float* W1   = (const float*)d_in[3];
    const float* b1   = (const float*)d_in[4];
    const float* W2   = (const float*)d_in[5];
    const float* b2   = (const float*)d_in[6];
    const float* Wlin = (const float*)d_in[7];
    const float* blin = (const float*)d_in[8];

    const int N = in_sizes[2];      // 100000
    const int E = in_sizes[1] / 2;  // 3200000
    const int G = out_size / 2;     // 512
    const int* src  = ei;
    const int* dstv = ei + E;

    // ---- workspace layout ----
    int*   deg      = (int*)d_ws;             // N
    int*   cursor   = deg + N;                // N
    int*   blocksum = cursor + N;             // 256
    int*   csr_src  = blocksum + 256;         // E
    float* dinv     = (float*)(csr_src + E);  // N
    float* pool     = dinv + N;               // G*64
    float* cnt      = pool + (size_t)G * HF;  // G
    float* bufA     = cnt + G;                // N*64
    float* bufB     = bufA + (size_t)N * HF;  // N*64

    int nb = (N + 1023) / 1024;

    // ---- CSR build (once, reused by both convs) ----
    hipMemsetAsync(deg, 0, (size_t)N * sizeof(int), stream);
    hist_kernel<<<(E + 255) / 256, 256, 0, stream>>>(dstv, deg, E);
    scan_partial<<<nb, 256, 0, stream>>>(deg, blocksum, N);
    scan_blocksums<<<1, 256, 0, stream>>>(blocksum, nb);
    scan_apply<<<nb, 256, 0, stream>>>(deg, blocksum, cursor, dinv, N);
    const int part = (N + 7) / 8;
    const int nblk = 512;
    fill_kernel<<<8 * nblk, 256, 0, stream>>>(src, dstv, cursor, csr_src, E, part, nblk);

    // ---- conv1: bufA = (x@W1)*dinv ; bufB = relu(aggregate) ----
    gemm_scale_kernel<128><<<(N + 31) / 32, 256, 0, stream>>>(x, W1, dinv, bufA, N);
    agg_relu_kernel<<<(N + 3) / 4, 256, 0, stream>>>(bufA, cursor, deg, csr_src, dinv, b1,
                                                     bufB, N);

    // ---- conv2: bufA = (h1@W2)*dinv ; aggregate + relu + pool ----
    gemm_scale_kernel<64><<<(N + 31) / 32, 256, 0, stream>>>(bufB, W2, dinv, bufA, N);
    hipMemsetAsync(pool, 0, ((size_t)G * HF + G) * sizeof(float), stream);
    agg_pool_kernel<<<(N + 3) / 4, 256, 0, stream>>>(bufA, cursor, deg, csr_src, dinv, b2,
                                                     bat, pool, cnt, N);

    final_kernel<<<G, HF, 0, stream>>>(pool, cnt, Wlin, blin, (float*)d_out);
}